// Round 1
// baseline (79.555 us; speedup 1.0000x reference)
//
#include <hip/hip_runtime.h>

// Problem constants: L=36, G=180, A=0.2, RO=2.5, RMAX=13, B=27, CELLS=27^3=19683
// NRAD=8, NL=4 -> 16 masked (l,m) pairs, VCELL=0.008
//
// V2: radial split. Each block handles 4 of the 8 radial functions
// (nh = blockIdx.x>>3), so acc[] is 64 floats instead of 128 ->
// ~half the VGPRs -> 4 waves/SIMD instead of 2 (the v1 bottleneck was
// latency at 25% occupancy, not VALU throughput: ~2.5us of VALU vs ~30us
// measured). Geometry+load run twice per cell (+~30% VALU) -- a good
// trade while stall-bound. s and VCELL-independent Y constants are folded
// into the radial power chain so no ys[16] array is materialized.
#define G 180
#define RO_F 2.5f
#define A_F 0.2f
#define VCELL_F 0.008f
#define CELLS 19683
#define SLABS 8
#define NATOMS 64

// lm ordering (matches coeff[:, MASK].reshape(-1)):
// 0:(0,0) 1:(1,-1) 2:(1,0) 3:(1,1) 4:(2,-2) 5:(2,-1) 6:(2,0) 7:(2,1) 8:(2,2)
// 9:(3,-3) 10:(3,-2) 11:(3,-1) 12:(3,0) 13:(3,1) 14:(3,2) 15:(3,3)

// ws layout: ws[atom][nh][slab][64]; every slot fully overwritten each call
// (no atomics, no zero-init -> safe vs 0xAA poison).
__global__ __launch_bounds__(256, 4) void proj_kernel(
    const float* __restrict__ rho, const float* __restrict__ pos,
    float* __restrict__ ws)
{
    const int atom = blockIdx.y;
    const int slab = blockIdx.x & (SLABS - 1);
    const int nh   = blockIdx.x >> 3;        // 0: n=0..3, 1: n=4..7
    const int tid  = threadIdx.x;
    const int lane = tid & 63;
    const int waveid = tid >> 6;

    const float px = pos[atom*3+0], py = pos[atom*3+1], pz = pos[atom*3+2];
    // cm = round(pos/A); dr = pos - A*cm   (A = 0.2 -> pos*5)
    const float cmx = rintf(px * 5.0f), cmy = rintf(py * 5.0f), cmz = rintf(pz * 5.0f);
    const float drx = px - A_F*cmx, dry = py - A_F*cmy, drz = pz - A_F*cmz;
    const int icx = (int)cmx - 13, icy = (int)cmy - 13, icz = (int)cmz - 13;

    float acc[64];
    #pragma unroll
    for (int j = 0; j < 64; ++j) acc[j] = 0.0f;

    for (int c = slab*256 + tid; c < CELLS; c += SLABS*256) {
        int i = c / 729;
        int rem = c - i*729;
        int j = rem / 27;
        int k = rem - j*27;
        // periodic wrap: i+icx in [-13, 193]
        int gx = i + icx; gx += (gx < 0) ? G : 0; gx -= (gx >= G) ? G : 0;
        int gy = j + icy; gy += (gy < 0) ? G : 0; gy -= (gy >= G) ? G : 0;
        int gz = k + icz; gz += (gz < 0) ? G : 0; gz -= (gz >= G) ? G : 0;
        float s = rho[(gx*G + gy)*G + gz];

        float x = (float)(i-13)*A_F - drx;
        float y = (float)(j-13)*A_F - dry;
        float z = (float)(k-13)*A_F - drz;
        float r2 = x*x + y*y + z*z;
        float inv = rsqrtf(fmaxf(r2, 1e-24f));
        float R = r2 * inv;                 // == sqrt(r2)
        if (R < RO_F) {
            float t = RO_F - R;
            float t2 = t * t;
            float pb = r2 * t2 * s;         // phi_0 * s; s folded into powers
            if (nh) pb *= t2 * t2;          // start at phi_4 for upper half
            float p0 = pb, p1 = pb*t, p2 = p1*t, p3 = p2*t;

            float ux = x*inv, uy = y*inv, uz = z*inv;
            float ux2 = ux*ux, uy2 = uy*uy, uz2 = uz*uz;
            float xy = ux*uy, yz = uy*uz, xz = ux*uz;

            // acc index = klocal*16 + q  (klocal = n - 4*nh)
            #define ACC4(Q, Y) { float yv = (Y); \
                acc[Q]      = fmaf(p0, yv, acc[Q]); \
                acc[16 + Q] = fmaf(p1, yv, acc[16 + Q]); \
                acc[32 + Q] = fmaf(p2, yv, acc[32 + Q]); \
                acc[48 + Q] = fmaf(p3, yv, acc[48 + Q]); }

            ACC4(0,  0.28209479177f);
            ACC4(1,  0.48860251190f * uy);
            ACC4(2,  0.48860251190f * uz);
            ACC4(3,  0.48860251190f * ux);
            ACC4(4,  1.09254843059f * xy);              // 2 * 0.54627 * ux uy
            ACC4(5,  1.09254843059f * yz);
            ACC4(6,  0.31539156525f * (3.0f*uz2 - 1.0f));
            ACC4(7,  1.09254843059f * xz);
            ACC4(8,  0.54627421530f * (ux2 - uy2));
            ACC4(9,  0.59004358993f * uy*(3.0f*ux2 - uy2));
            ACC4(10, 2.89061144264f * xy*uz);           // 2 * 1.44530572
            ACC4(11, 0.45704579946f * uy*(5.0f*uz2 - 1.0f));
            ACC4(12, 0.37317633259f * uz*(5.0f*uz2 - 3.0f));
            ACC4(13, 0.45704579946f * ux*(5.0f*uz2 - 1.0f));
            ACC4(14, 1.44530572132f * (ux2 - uy2)*uz);
            ACC4(15, 0.59004358993f * ux*(ux2 - 3.0f*uy2));
            #undef ACC4
        }
    }

    // Block reduction, no atomics (2 chunks of 32 combos now):
    //  stage 1: per-wave LDS transpose (pad 33 -> conflict-free), each lane
    //           sums a 32-row half-column -> partial per (wave, half, col)
    //  stage 2: 8 partials per output idx gathered by tid<64
    __shared__ float red[4][64][33];      // 33 KB
    __shared__ float stage[2][8][32];     // 2 KB
    const int col  = lane & 31;
    const int half = lane >> 5;
    #pragma unroll
    for (int cb = 0; cb < 2; ++cb) {
        __syncthreads();                  // WAR: previous chunk's reads done
        #pragma unroll
        for (int q = 0; q < 32; ++q)
            red[waveid][lane][q] = acc[cb*32 + q];
        __syncthreads();
        float csum = 0.0f;
        #pragma unroll
        for (int r = 0; r < 32; ++r)
            csum += red[waveid][half*32 + r][col];
        stage[cb][waveid*2 + half][col] = csum;
    }
    __syncthreads();
    if (tid < 64) {
        const int cb = tid >> 5, c2 = tid & 31;
        float sum = 0.0f;
        #pragma unroll
        for (int r = 0; r < 8; ++r)
            sum += stage[cb][r][c2];
        ws[((atom*2 + nh)*SLABS + slab)*64 + tid] = sum;
    }
}

// out[atom][n*16+q] = VCELL * sum_k W[n][k] * (sum_slab ws[atom][k>>2][slab][(k&3)*16+q])
__global__ void finalize_kernel(const float* __restrict__ ws,
                                const float* __restrict__ W,
                                float* __restrict__ out)
{
    const int atom = blockIdx.x;
    const int t = threadIdx.x;        // 128 threads
    const int n = t >> 4, q = t & 15;
    const float* base = ws + atom*2*SLABS*64;
    float red[8];
    #pragma unroll
    for (int k = 0; k < 8; ++k) {
        const float* hb = base + (k >> 2)*SLABS*64 + (k & 3)*16 + q;
        float sk = 0.0f;
        #pragma unroll
        for (int s = 0; s < 8; ++s)
            sk += hb[s*64];
        red[k] = sk;
    }
    float sum = 0.0f;
    #pragma unroll
    for (int k = 0; k < 8; ++k)
        sum = fmaf(W[n*8+k], red[k], sum);
    out[atom*128 + t] = sum * VCELL_F;
}

extern "C" void kernel_launch(void* const* d_in, const int* in_sizes, int n_in,
                              void* d_out, int out_size, void* d_ws, size_t ws_size,
                              hipStream_t stream) {
    const float* rho = (const float*)d_in[0];   // 180^3
    const float* pos = (const float*)d_in[1];   // 64 x 3
    const float* W   = (const float*)d_in[2];   // 8 x 8
    float* out = (float*)d_out;                 // 64 x 128 fp32
    float* ws  = (float*)d_ws;                  // 64*2*8*64 fp32 partials

    dim3 grid(SLABS*2, NATOMS);                 // x = slab | (nh<<3)
    proj_kernel<<<grid, 256, 0, stream>>>(rho, pos, ws);
    finalize_kernel<<<NATOMS, 128, 0, stream>>>(ws, W, out);
}

// Round 2
// 77.621 us; speedup vs baseline: 1.0249x; 1.0249x over previous
//
#include <hip/hip_runtime.h>

// Problem constants: L=36, G=180, A=0.2, RO=2.5, RMAX=13, B=27, CELLS=27^3=19683
// NRAD=8, NL=4 -> 16 masked (l,m) pairs, VCELL=0.008
//
// V3: single pass over rho (revert v2's nh split) + max MLP.
// Diagnosis: v1/v2 were cold-HBM-latency-bound on the scattered rho gathers
// (the harness's 256 MiB poison fill evicts rho from L2/L3 every timed
// iteration). v1's loop had a data-dependent trip count (c < CELLS), so the
// compiler couldn't unroll -> ~10 serialized ~900-cyc loads per thread.
// v2 doubled occupancy but also doubled the loads -> exact wash (observed).
// Fix: compile-time 10-iteration unroll; issue all 10 loads into statically
// indexed registers first, then compute. Latency paid once, 10 loads in
// flight per thread.
#define G 180
#define RO_F 2.5f
#define A_F 0.2f
#define VCELL_F 0.008f
#define CELLS 19683
#define SLABS 8
#define NATOMS 64
#define ITERS 10                 // ceil(19683 / (8*256))

// lm ordering (matches coeff[:, MASK].reshape(-1)):
// 0:(0,0) 1:(1,-1) 2:(1,0) 3:(1,1) 4:(2,-2) 5:(2,-1) 6:(2,0) 7:(2,1) 8:(2,2)
// 9:(3,-3) 10:(3,-2) 11:(3,-1) 12:(3,0) 13:(3,1) 14:(3,2) 15:(3,3)

// ws layout: ws[atom][slab][128]; every slot fully overwritten each call
// (no atomics, no zero-init -> safe vs 0xAA poison).
__global__ __launch_bounds__(256, 2) void proj_kernel(
    const float* __restrict__ rho, const float* __restrict__ pos,
    float* __restrict__ ws)
{
    const int atom = blockIdx.y;
    const int slab = blockIdx.x;
    const int tid  = threadIdx.x;
    const int lane = tid & 63;
    const int waveid = tid >> 6;

    const float px = pos[atom*3+0], py = pos[atom*3+1], pz = pos[atom*3+2];
    // cm = round(pos/A); dr = pos - A*cm   (A = 0.2 -> pos*5)
    const float cmx = rintf(px * 5.0f), cmy = rintf(py * 5.0f), cmz = rintf(pz * 5.0f);
    const float drx = px - A_F*cmx, dry = py - A_F*cmy, drz = pz - A_F*cmz;
    const int icx = (int)cmx - 13, icy = (int)cmy - 13, icz = (int)cmz - 13;

    const int base = slab*256 + tid;

    // ---- Prefetch phase: all ITERS loads issued back-to-back ----
    // Only the last iteration can run past CELLS (base<2048, 9*2048=18432,
    // 18432+2047 < 2*CELLS): clamp its address to 0 and zero its sample.
    float sv[ITERS];
    #pragma unroll
    for (int it = 0; it < ITERS; ++it) {
        int c = base + it*2048;
        bool ok = (it < ITERS-1) || (c < CELLS);
        int cc = ok ? c : 0;
        int i = cc / 729;
        int rem = cc - i*729;
        int j = rem / 27;
        int k = rem - j*27;
        // periodic wrap: i+icx in [-13, 193]
        int gx = i + icx; gx += (gx < 0) ? G : 0; gx -= (gx >= G) ? G : 0;
        int gy = j + icy; gy += (gy < 0) ? G : 0; gy -= (gy >= G) ? G : 0;
        int gz = k + icz; gz += (gz < 0) ? G : 0; gz -= (gz >= G) ? G : 0;
        float s = rho[(gx*G + gy)*G + gz];
        sv[it] = ok ? s : 0.0f;   // s folded into radial powers -> 0 kills cell
    }

    float acc[128];
    #pragma unroll
    for (int j = 0; j < 128; ++j) acc[j] = 0.0f;

    // ---- Compute phase (statically unrolled; sv[] indices compile-time) ----
    #pragma unroll
    for (int it = 0; it < ITERS; ++it) {
        int c = base + it*2048;
        int cc = ((it < ITERS-1) || (c < CELLS)) ? c : 0;
        int i = cc / 729;
        int rem = cc - i*729;
        int j = rem / 27;
        int k = rem - j*27;
        float s = sv[it];

        float x = (float)(i-13)*A_F - drx;
        float y = (float)(j-13)*A_F - dry;
        float z = (float)(k-13)*A_F - drz;
        float r2 = x*x + y*y + z*z;
        float inv = rsqrtf(fmaxf(r2, 1e-24f));
        float R = r2 * inv;                 // == sqrt(r2)
        if (R < RO_F) {
            float t = RO_F - R;
            float ux = x*inv, uy = y*inv, uz = z*inv;
            float uz2 = uz*uz;
            float ux2 = ux*ux, uy2 = uy*uy;
            float ys[16];
            ys[0]  = 0.28209479177f * s;
            ys[1]  = 0.48860251190f * uy * s;
            ys[2]  = 0.48860251190f * uz * s;
            ys[3]  = 0.48860251190f * ux * s;
            ys[4]  = 1.09254843059f * ux*uy * s;            // 2 * 0.54627
            ys[5]  = 1.09254843059f * uy*uz * s;
            ys[6]  = 0.31539156525f * (3.0f*uz2 - 1.0f) * s;
            ys[7]  = 1.09254843059f * ux*uz * s;
            ys[8]  = 0.54627421530f * (ux2 - uy2) * s;
            ys[9]  = 0.59004358993f * uy*(3.0f*ux2 - uy2) * s;
            ys[10] = 2.89061144264f * ux*uy*uz * s;         // 2 * 1.44530572
            ys[11] = 0.45704579946f * uy*(5.0f*uz2 - 1.0f) * s;
            ys[12] = 0.37317633259f * uz*(5.0f*uz2 - 3.0f) * s;
            ys[13] = 0.45704579946f * ux*(5.0f*uz2 - 1.0f) * s;
            ys[14] = 1.44530572132f * (ux2 - uy2)*uz * s;
            ys[15] = 0.59004358993f * ux*(ux2 - 3.0f*uy2) * s;

            float p = r2 * t * t;           // phi_0 = R^2 (RO-R)^2
            #pragma unroll
            for (int n = 0; n < 8; ++n) {
                #pragma unroll
                for (int q = 0; q < 16; ++q)
                    acc[n*16+q] = fmaf(p, ys[q], acc[n*16+q]);
                p *= t;                     // phi_{n+1} = phi_n * (RO-R)
            }
        }
    }

    // Block reduction, no atomics:
    //  stage 1: per-wave LDS transpose (pad 33 -> conflict-free), each lane
    //           sums a 32-row half-column -> partial per (wave, half, col)
    //  stage 2: 8 partials per output idx gathered by tid<128
    __shared__ float red[4][64][33];      // 33 KB
    __shared__ float stage[4][8][32];     // 4 KB
    const int col  = lane & 31;
    const int half = lane >> 5;
    #pragma unroll
    for (int cb = 0; cb < 4; ++cb) {
        __syncthreads();                  // WAR: previous chunk's reads done
        #pragma unroll
        for (int q = 0; q < 32; ++q)
            red[waveid][lane][q] = acc[cb*32 + q];
        __syncthreads();
        float csum = 0.0f;
        #pragma unroll
        for (int r = 0; r < 32; ++r)
            csum += red[waveid][half*32 + r][col];
        stage[cb][waveid*2 + half][col] = csum;
    }
    __syncthreads();
    if (tid < 128) {
        const int cb = tid >> 5, c2 = tid & 31;
        float sum = 0.0f;
        #pragma unroll
        for (int r = 0; r < 8; ++r)
            sum += stage[cb][r][c2];
        ws[(atom*SLABS + slab)*128 + tid] = sum;
    }
}

// out[atom][n*16+q] = VCELL * sum_k W[n][k] * (sum_slab ws[atom][slab][k*16+q])
__global__ void finalize_kernel(const float* __restrict__ ws,
                                const float* __restrict__ W,
                                float* __restrict__ out)
{
    const int atom = blockIdx.x;
    const int t = threadIdx.x;        // 128 threads
    const int n = t >> 4, q = t & 15;
    const float* base = ws + atom*SLABS*128;
    float red[8];
    #pragma unroll
    for (int k = 0; k < 8; ++k) {
        float sk = 0.0f;
        #pragma unroll
        for (int s = 0; s < 8; ++s)
            sk += base[s*128 + k*16 + q];
        red[k] = sk;
    }
    float sum = 0.0f;
    #pragma unroll
    for (int k = 0; k < 8; ++k)
        sum = fmaf(W[n*8+k], red[k], sum);
    out[atom*128 + t] = sum * VCELL_F;
}

extern "C" void kernel_launch(void* const* d_in, const int* in_sizes, int n_in,
                              void* d_out, int out_size, void* d_ws, size_t ws_size,
                              hipStream_t stream) {
    const float* rho = (const float*)d_in[0];   // 180^3
    const float* pos = (const float*)d_in[1];   // 64 x 3
    const float* W   = (const float*)d_in[2];   // 8 x 8
    float* out = (float*)d_out;                 // 64 x 128 fp32
    float* ws  = (float*)d_ws;                  // 64*8*128 fp32 partials

    dim3 grid(SLABS, NATOMS);
    proj_kernel<<<grid, 256, 0, stream>>>(rho, pos, ws);
    finalize_kernel<<<NATOMS, 128, 0, stream>>>(ws, W, out);
}

// Round 4
// 76.193 us; speedup vs baseline: 1.0441x; 1.0187x over previous
//
#include <hip/hip_runtime.h>

// Problem constants: L=36, G=180, A=0.2, RO=2.5, RMAX=13, B=27, CELLS=27^3=19683
// NRAD=8, NL=4 -> 16 masked (l,m) pairs, VCELL=0.008
//
// V4b: resubmit of V4 (round-3 bench was an infra failure: container died
// twice, no kernel verdict). Only change vs V4: the two intra-wave
// wave_barrier() ordering hints are replaced with uniform __syncthreads()
// (identical correctness, ~100 cycles total) to rule out the one
// non-vanilla construct in case the container death was kernel-correlated.
//
// V4 content:
//  (a) float2-packed accumulate -> v_pk_fma_f32 (full-rate packed fp32;
//      scalar fma is half-rate on gfx950): 64 pk-fma/cell vs 128 fma.
//  (b) b128 LDS reduction: intra-wave transpose with ds_write_b128/
//      ds_read_b128 (68 wide ops/thread vs 256 scalar), bank-safe layout
//      (row stride 36 floats == 4 mod 32 -> only free 2-way aliasing).
// Rationale: v1/v2/v3 A/B showed the gather path costs only ~2-4 us total
// (doubling it in v2 cost +1.6 us); the reduction + unpacked FMA were the
// invariant terms across all three ~78 us results.
#define G 180
#define RO_F 2.5f
#define A_F 0.2f
#define VCELL_F 0.008f
#define CELLS 19683
#define SLABS 8
#define NATOMS 64
#define ITERS 10                 // ceil(19683 / (8*256))

typedef float f2 __attribute__((ext_vector_type(2)));
typedef float f4 __attribute__((ext_vector_type(4)));

// lm ordering (matches coeff[:, MASK].reshape(-1)):
// 0:(0,0) 1:(1,-1) 2:(1,0) 3:(1,1) 4:(2,-2) 5:(2,-1) 6:(2,0) 7:(2,1) 8:(2,2)
// 9:(3,-3) 10:(3,-2) 11:(3,-1) 12:(3,0) 13:(3,1) 14:(3,2) 15:(3,3)

// ws layout: ws[atom][slab][128]; every slot fully overwritten each call
// (no atomics, no zero-init -> safe vs 0xAA poison).
__global__ __launch_bounds__(256, 2) void proj_kernel(
    const float* __restrict__ rho, const float* __restrict__ pos,
    float* __restrict__ ws)
{
    const int atom = blockIdx.y;
    const int slab = blockIdx.x;
    const int tid  = threadIdx.x;
    const int lane = tid & 63;
    const int waveid = tid >> 6;

    const float px = pos[atom*3+0], py = pos[atom*3+1], pz = pos[atom*3+2];
    // cm = round(pos/A); dr = pos - A*cm   (A = 0.2 -> pos*5)
    const float cmx = rintf(px * 5.0f), cmy = rintf(py * 5.0f), cmz = rintf(pz * 5.0f);
    const float drx = px - A_F*cmx, dry = py - A_F*cmy, drz = pz - A_F*cmz;
    const int icx = (int)cmx - 13, icy = (int)cmy - 13, icz = (int)cmz - 13;

    const int base = slab*256 + tid;

    // ---- Prefetch phase: all ITERS loads issued back-to-back ----
    // Only the last iteration can run past CELLS: clamp addr, zero sample
    // (s is folded into the radial powers, so s=0 kills the cell).
    float sv[ITERS];
    #pragma unroll
    for (int it = 0; it < ITERS; ++it) {
        int c = base + it*2048;
        bool ok = (it < ITERS-1) || (c < CELLS);
        int cc = ok ? c : 0;
        int i = cc / 729;
        int rem = cc - i*729;
        int j = rem / 27;
        int k = rem - j*27;
        int gx = i + icx; gx += (gx < 0) ? G : 0; gx -= (gx >= G) ? G : 0;
        int gy = j + icy; gy += (gy < 0) ? G : 0; gy -= (gy >= G) ? G : 0;
        int gz = k + icz; gz += (gz < 0) ? G : 0; gz -= (gz >= G) ? G : 0;
        float s = rho[(gx*G + gy)*G + gz];
        sv[it] = ok ? s : 0.0f;
    }

    // acc2[n*8+q] packs coeff pair (n*16+2q, n*16+2q+1)
    f2 acc2[64];
    #pragma unroll
    for (int j = 0; j < 64; ++j) acc2[j] = (f2){0.0f, 0.0f};

    // ---- Compute phase (statically unrolled) ----
    #pragma unroll
    for (int it = 0; it < ITERS; ++it) {
        int c = base + it*2048;
        int cc = ((it < ITERS-1) || (c < CELLS)) ? c : 0;
        int i = cc / 729;
        int rem = cc - i*729;
        int j = rem / 27;
        int k = rem - j*27;
        float s = sv[it];

        float x = (float)(i-13)*A_F - drx;
        float y = (float)(j-13)*A_F - dry;
        float z = (float)(k-13)*A_F - drz;
        float r2 = x*x + y*y + z*z;
        float inv = rsqrtf(fmaxf(r2, 1e-24f));
        float R = r2 * inv;                 // == sqrt(r2)
        if (R < RO_F) {
            float t = RO_F - R;
            float ux = x*inv, uy = y*inv, uz = z*inv;
            float uz2 = uz*uz;
            float ux2 = ux*ux, uy2 = uy*uy;
            float xy = ux*uy, yz = uy*uz, xz = ux*uz;
            // ysv[q] = { ys[2q], ys[2q+1] } with s folded in
            f2 ysv[8];
            ysv[0] = (f2){ 0.28209479177f * s,
                           0.48860251190f * uy * s };
            ysv[1] = (f2){ 0.48860251190f * uz * s,
                           0.48860251190f * ux * s };
            ysv[2] = (f2){ 1.09254843059f * xy * s,      // 2 * 0.54627
                           1.09254843059f * yz * s };
            ysv[3] = (f2){ 0.31539156525f * (3.0f*uz2 - 1.0f) * s,
                           1.09254843059f * xz * s };
            ysv[4] = (f2){ 0.54627421530f * (ux2 - uy2) * s,
                           0.59004358993f * uy*(3.0f*ux2 - uy2) * s };
            ysv[5] = (f2){ 2.89061144264f * xy*uz * s,   // 2 * 1.44530572
                           0.45704579946f * uy*(5.0f*uz2 - 1.0f) * s };
            ysv[6] = (f2){ 0.37317633259f * uz*(5.0f*uz2 - 3.0f) * s,
                           0.45704579946f * ux*(5.0f*uz2 - 1.0f) * s };
            ysv[7] = (f2){ 1.44530572132f * (ux2 - uy2)*uz * s,
                           0.59004358993f * ux*(ux2 - 3.0f*uy2) * s };

            float p = r2 * t * t;           // phi_0 = R^2 (RO-R)^2
            #pragma unroll
            for (int n = 0; n < 8; ++n) {
                f2 pv = (f2){p, p};
                #pragma unroll
                for (int q = 0; q < 8; ++q)
                    acc2[n*8+q] += pv * ysv[q];   // v_pk_fma_f32
                p *= t;                     // phi_{n+1} = phi_n * (RO-R)
            }
        }
    }

    // ---- Reduction: 4 chunks of 32 combos, b128 intra-wave transpose ----
    // red4 row stride = 9 f4 = 36 floats == 4 mod 32 banks -> writes and
    // reads alias at most 2 lanes/bank within a 16-lane phase (free, m136).
    // Each wave only touches its own red4[waveid] slice; __syncthreads is
    // uniform (all 256 threads reach every barrier).
    __shared__ f4 red4[4][64][9];      // 36.9 KB
    __shared__ f4 stage4[4][32][9];    // 18.4 KB
    const int rq = lane >> 3, qd = lane & 7;
    #pragma unroll
    for (int ch = 0; ch < 4; ++ch) {
        #pragma unroll
        for (int k = 0; k < 8; ++k) {
            f2 a0 = acc2[ch*16 + 2*k];
            f2 a1 = acc2[ch*16 + 2*k + 1];
            red4[waveid][lane][k] = (f4){a0[0], a0[1], a1[0], a1[1]};
        }
        __syncthreads();                   // order write->read
        f4 s4 = (f4){0.0f, 0.0f, 0.0f, 0.0f};
        #pragma unroll
        for (int r = 0; r < 8; ++r)
            s4 += red4[waveid][rq*8 + r][qd];
        stage4[ch][waveid*8 + rq][qd] = s4;
        __syncthreads();                   // order read->next-chunk-write
    }
    if (tid < 128) {
        const int ch = tid >> 5, qd2 = (tid & 31) >> 2, e = tid & 3;
        float sum = 0.0f;
        #pragma unroll
        for (int r = 0; r < 32; ++r)
            sum += stage4[ch][r][qd2][e];
        ws[(atom*SLABS + slab)*128 + tid] = sum;
    }
}

// out[atom][n*16+q] = VCELL * sum_k W[n][k] * (sum_slab ws[atom][slab][k*16+q])
__global__ void finalize_kernel(const float* __restrict__ ws,
                                const float* __restrict__ W,
                                float* __restrict__ out)
{
    const int atom = blockIdx.x;
    const int t = threadIdx.x;        // 128 threads
    const int n = t >> 4, q = t & 15;
    const float* base = ws + atom*SLABS*128;
    float red[8];
    #pragma unroll
    for (int k = 0; k < 8; ++k) {
        float sk = 0.0f;
        #pragma unroll
        for (int s = 0; s < 8; ++s)
            sk += base[s*128 + k*16 + q];
        red[k] = sk;
    }
    float sum = 0.0f;
    #pragma unroll
    for (int k = 0; k < 8; ++k)
        sum = fmaf(W[n*8+k], red[k], sum);
    out[atom*128 + t] = sum * VCELL_F;
}

extern "C" void kernel_launch(void* const* d_in, const int* in_sizes, int n_in,
                              void* d_out, int out_size, void* d_ws, size_t ws_size,
                              hipStream_t stream) {
    const float* rho = (const float*)d_in[0];   // 180^3
    const float* pos = (const float*)d_in[1];   // 64 x 3
    const float* W   = (const float*)d_in[2];   // 8 x 8
    float* out = (float*)d_out;                 // 64 x 128 fp32
    float* ws  = (float*)d_ws;                  // 64*8*128 fp32 partials

    dim3 grid(SLABS, NATOMS);
    proj_kernel<<<grid, 256, 0, stream>>>(rho, pos, ws);
    finalize_kernel<<<NATOMS, 128, 0, stream>>>(ws, W, out);
}